// Round 8
// baseline (91.421 us; speedup 1.0000x reference)
//
#include <hip/hip_runtime.h>

// FerroelectricBasisConv2d on MI355X — round 8.
// Math (validated R6/R7, absmax 0.5):
//   w = x + Ec;  r = rsqrt(w*w+0.04);  arg = G*w + S*(w*r - 1)
//   u = rcp(exp2(arg)+1);  contribution = (Ps*c+b*c) + A*u
//   G = 2*log2e*k, S = 0.1*G*Ec, A = -2*Ps*c
//
// R8: params out of LDS, into SGPRs. Prep transforms tuples into ws
// ([co][cin][ij][kk] float4) + per-co constant. In main, every lane of a
// wave processes the SAME tuple: wave = (row-pair, cin-half) via
// readfirstlane (SGPR), lane = (row-parity, col). Param index is therefore
// wave-uniform -> s_load_dwordx4 on the scalar pipe: the hot loop's only
// vector memory op is one ds_read_b32 per 3 evals (x value).
// Grid 1024 = (b4, co32, row-quad8), 256 thr, 4 waves: w = rp*2 + ch.
// Final: LDS partial (4x64) combine across cin-halves, store once.

#define LOG2E 1.4426950408889634f

__global__ __launch_bounds__(512) void ferro_prep(
    const float* __restrict__ k, const float* __restrict__ Ec,
    const float* __restrict__ Ps, const float* __restrict__ bias,
    const float* __restrict__ coef, const float* __restrict__ out_bias,
    float4* __restrict__ p4g, float* __restrict__ cg)
{
    const int co  = blockIdx.x;       // 0..31
    const int tid = threadIdx.x;      // 0..511
    __shared__ float red[8];

    const int pbase = co * 432;
    float cpart = 0.f;
    if (tid < 432) {
        float kv = k[pbase + tid];
        float ev = Ec[pbase + tid];
        float pv = Ps[pbase + tid];
        float bv = bias[pbase + tid];
        float cv = coef[pbase + tid];
        float G  = 2.f * LOG2E * kv;
        float4 v;
        v.x = ev;                  // Ec
        v.y = G;                   // G
        v.z = 0.1f * G * ev;       // S
        v.w = -2.f * pv * cv;      // A
        // src tid = cin*27 + kk*9 + ij  ->  dst = cin*27 + ij*3 + kk
        int cin = tid / 27;
        int r   = tid - cin * 27;
        int kk  = r / 9;
        int ij  = r - kk * 9;
        p4g[pbase + cin * 27 + ij * 3 + kk] = v;
        cpart = (pv + bv) * cv;
    }
    #pragma unroll
    for (int off = 32; off > 0; off >>= 1)
        cpart += __shfl_down(cpart, off, 64);
    if ((tid & 63) == 0) red[tid >> 6] = cpart;
    __syncthreads();
    if (tid == 0) {
        float t = 0.f;
        #pragma unroll
        for (int w = 0; w < 8; ++w) t += red[w];
        cg[co] = t + out_bias[co];
    }
}

__global__ __launch_bounds__(256, 4) void ferro_main(
    const float* __restrict__ x,
    const float4* __restrict__ p4g, const float* __restrict__ cg,
    float* __restrict__ out)
{
    // bid = b*256 + co*8 + rq
    const int bid = blockIdx.x;
    const int rq  = bid & 7;          // 8 row-quads (4 rows each)
    const int co  = (bid >> 3) & 31;
    const int b   = bid >> 8;
    const int tid = threadIdx.x;

    __shared__ float xs[16 * 6 * 34];  // [cin16][row6][col34], rows r0-1..r0+4
    __shared__ float red[4 * 64];      // [wave][lane] partials

    // ---- stage x: 16 cins, rows r0-1..r0+4, cols -1..32 (zero pad) ----
    const int r0 = rq * 4;
    const float* xb = x + b * (16 * 1024);
    for (int idx = tid; idx < 16 * 204; idx += 256) {
        int cin  = idx / 204;
        int rem  = idx - cin * 204;
        int row6 = rem / 34;
        int colp = rem - row6 * 34;
        int gr = r0 + row6 - 1;
        int gc = colp - 1;
        float v = 0.f;
        if ((unsigned)gr < 32u && (unsigned)gc < 32u)
            v = xb[(cin * 32 + gr) * 32 + gc];
        xs[idx] = v;
    }
    __syncthreads();

    // ---- wave decomposition (SGPR-uniform cin) ----
    const int wb   = __builtin_amdgcn_readfirstlane(tid) >> 6;  // wave id 0..3
    const int rp   = wb >> 1;          // row-pair within quad
    const int ch   = wb & 1;           // cin-half
    const int lane = tid & 63;
    const int prow = lane >> 5;        // row parity
    const int col  = lane & 31;

    // lane's pixel: local row lr = rp*2 + prow; xs row for tap i is lr + i
    const int lrbase = rp * 2 + prow;
    float acc0 = 0.f, acc1 = 0.f, acc2 = 0.f;

    #pragma unroll 1
    for (int c8 = 0; c8 < 8; ++c8) {
        const int cin = ch * 8 + c8;                       // SGPR
        const float*  xr = &xs[cin * 204 + lrbase * 34 + col];
        const float4* pp = &p4g[(co * 16 + cin) * 27];     // uniform base
        #pragma unroll
        for (int ij = 0; ij < 9; ++ij) {
            const int i = ij / 3, j = ij - (ij / 3) * 3;
            float xv = xr[i * 34 + j];
            {
                float4 v = pp[ij * 3 + 0];                 // s_load_dwordx4
                float wv = xv + v.x;
                float q  = fmaf(wv, wv, 0.04f);
                float r  = __builtin_amdgcn_rsqf(q);
                float t  = fmaf(wv, r, -1.f);
                float a  = fmaf(v.z, t, v.y * wv);
                float e  = __builtin_amdgcn_exp2f(a);
                float u  = __builtin_amdgcn_rcpf(e + 1.f);
                acc0 = fmaf(v.w, u, acc0);
            }
            {
                float4 v = pp[ij * 3 + 1];
                float wv = xv + v.x;
                float q  = fmaf(wv, wv, 0.04f);
                float r  = __builtin_amdgcn_rsqf(q);
                float t  = fmaf(wv, r, -1.f);
                float a  = fmaf(v.z, t, v.y * wv);
                float e  = __builtin_amdgcn_exp2f(a);
                float u  = __builtin_amdgcn_rcpf(e + 1.f);
                acc1 = fmaf(v.w, u, acc1);
            }
            {
                float4 v = pp[ij * 3 + 2];
                float wv = xv + v.x;
                float q  = fmaf(wv, wv, 0.04f);
                float r  = __builtin_amdgcn_rsqf(q);
                float t  = fmaf(wv, r, -1.f);
                float a  = fmaf(v.z, t, v.y * wv);
                float e  = __builtin_amdgcn_exp2f(a);
                float u  = __builtin_amdgcn_rcpf(e + 1.f);
                acc2 = fmaf(v.w, u, acc2);
            }
        }
    }

    red[wb * 64 + lane] = (acc0 + acc1) + acc2;
    __syncthreads();

    // ---- combine cin-halves (wave pairs 2rp, 2rp+1), add const, store ----
    if (tid < 128) {
        int rp2 = tid >> 6;
        int ln  = tid & 63;
        float v = red[(rp2 * 2 + 0) * 64 + ln] + red[(rp2 * 2 + 1) * 64 + ln]
                + cg[co];
        int grow = r0 + rp2 * 2 + (ln >> 5);
        int gcol = ln & 31;
        out[((b * 32 + co) * 32 + grow) * 32 + gcol] = v;
    }
}

extern "C" void kernel_launch(void* const* d_in, const int* in_sizes, int n_in,
                              void* d_out, int out_size, void* d_ws, size_t ws_size,
                              hipStream_t stream) {
    const float* x        = (const float*)d_in[0];
    const float* k        = (const float*)d_in[1];
    const float* Ec       = (const float*)d_in[2];
    const float* Ps       = (const float*)d_in[3];
    const float* bias     = (const float*)d_in[4];
    const float* coef     = (const float*)d_in[5];
    const float* out_bias = (const float*)d_in[6];
    float* out = (float*)d_out;

    float4* p4g = (float4*)d_ws;                          // 32*432 float4
    float*  cg  = (float*)((char*)d_ws + 32 * 432 * 16);  // 32 float

    ferro_prep<<<dim3(32), dim3(512), 0, stream>>>(
        k, Ec, Ps, bias, coef, out_bias, p4g, cg);
    ferro_main<<<dim3(1024), dim3(256), 0, stream>>>(x, p4g, cg, out);
}

// Round 9
// 89.127 us; speedup vs baseline: 1.0257x; 1.0257x over previous
//
#include <hip/hip_runtime.h>

// FerroelectricBasisConv2d on MI355X — round 9.
// Math (validated R6/R7, absmax 0.5):
//   w = x + Ec;  r = rsqrt(w*w+0.04);  arg = G*w + S*(w*r - 1)
//       = fma(S*w, r, fma(G, w, -S))
//   u = rcp(exp2(arg)+1);  contribution = (Ps*c+b*c) + A*u
//   G = 2*log2e*k, S = 0.1*G*Ec, A = -2*Ps*c
//   Per-tuple float4 (Ec, G, S, A); per eval: 7 full-rate + 3 trans = 38 cy.
//
// R9: R7 structure + 2 pixels/lane to HALVE the param ds_read_b128 traffic
// (R7 pipe model: LDS 20us > issue 14us per CU -> LDS-bound; this drops LDS
// to ~11us, below the issue floor). (256,4) = 128-VGPR budget (no R6-style
// spill; >4 blocks/CU proven worthless in R4->R5).
// Grid 1024 = (b4, co32, row-quad8). Wave w -> cin quartet 4w..4w+3.
// Lane = col(32) x half(2): pixels (2*ph, col), (2*ph+1, col) of the quad.
// Cross-wave reduction over the 4 cin-quartets via LDS; store once/pixel.

#define LOG2E 1.4426950408889634f

__global__ __launch_bounds__(256, 4) void ferro_main(
    const float* __restrict__ x,
    const float* __restrict__ k, const float* __restrict__ Ec,
    const float* __restrict__ Ps, const float* __restrict__ bias,
    const float* __restrict__ coef, const float* __restrict__ out_bias,
    float* __restrict__ out)
{
    // bid = b*256 + co*8 + rq
    const int bid = blockIdx.x;
    const int rq  = bid & 7;          // 8 row-quads (4 rows each)
    const int co  = (bid >> 3) & 31;
    const int b   = bid >> 8;
    const int tid = threadIdx.x;

    __shared__ float4 p4s[432];        // [cin16][ij9][kk3]: (Ec, G, S, A)
    __shared__ float  xs[16 * 6 * 34]; // [cin16][row6][col34], rows r0-1..r0+4
    __shared__ float  red[4 * 128];    // [wave][lr4][col32]
    __shared__ float  redc[4];
    __shared__ float  csh;

    // ---- transform all 432 raw tuples for this co (one float4 each) ----
    const int pbase = co * 432;
    float cpart = 0.f;
    for (int s = tid; s < 432; s += 256) {
        float kv = k[pbase + s];
        float ev = Ec[pbase + s];
        float pv = Ps[pbase + s];
        float bv = bias[pbase + s];
        float cv = coef[pbase + s];
        float G  = 2.f * LOG2E * kv;
        float4 v;
        v.x = ev;                   // Ec
        v.y = G;                    // G
        v.z = 0.1f * G * ev;        // S
        v.w = -2.f * pv * cv;       // A
        // src s = cin*27 + kk*9 + ij  ->  dst = cin*27 + ij*3 + kk
        int cin = s / 27;
        int r   = s - cin * 27;
        int kk  = r / 9;
        int ij  = r - kk * 9;
        p4s[cin * 27 + ij * 3 + kk] = v;
        cpart += (pv + bv) * cv;
    }

    // ---- stage x: 16 cins, rows r0-1..r0+4, cols -1..32 (zero pad) ----
    const int r0 = rq * 4;
    const float* xb = x + b * (16 * 1024);
    for (int idx = tid; idx < 16 * 204; idx += 256) {
        int cin  = idx / 204;
        int rem  = idx - cin * 204;
        int row6 = rem / 34;
        int colp = rem - row6 * 34;
        int gr = r0 + row6 - 1;
        int gc = colp - 1;
        float v = 0.f;
        if ((unsigned)gr < 32u && (unsigned)gc < 32u)
            v = xb[(cin * 32 + gr) * 32 + gc];
        xs[idx] = v;
    }

    // ---- reduce per-cout constant ----
    #pragma unroll
    for (int off = 32; off > 0; off >>= 1)
        cpart += __shfl_down(cpart, off, 64);
    if ((tid & 63) == 0) redc[tid >> 6] = cpart;
    __syncthreads();
    if (tid == 0) csh = redc[0] + redc[1] + redc[2] + redc[3];
    __syncthreads();

    // ---- eval: wave w -> cins 4w..4w+3; lane -> (col, pixel-row-pair) ----
    const int w    = tid >> 6;
    const int lane = tid & 63;
    const int ph   = lane >> 5;        // row-pair half: rows 2ph, 2ph+1
    const int col  = lane & 31;
    float s00 = 0.f, s01 = 0.f, s02 = 0.f;   // pixel row 2ph
    float s10 = 0.f, s11 = 0.f, s12 = 0.f;   // pixel row 2ph+1

    #pragma unroll 1
    for (int c = 0; c < 4; ++c) {
        const int cin = w * 4 + c;
        const float*  xr = &xs[cin * 204 + (2 * ph) * 34 + col]; // xr[(i)*34+j] / +34
        const float4* pp = &p4s[cin * 27];
        #pragma unroll
        for (int ij = 0; ij < 9; ++ij) {
            const int i = ij / 3, j = ij - (ij / 3) * 3;
            float xv0 = xr[i * 34 + j];
            float xv1 = xr[i * 34 + 34 + j];
            #pragma unroll
            for (int kk = 0; kk < 3; ++kk) {
                float4 v = pp[ij * 3 + kk];
                // px0
                float w0 = xv0 + v.x;
                float q0 = fmaf(w0, w0, 0.04f);
                float r0_ = __builtin_amdgcn_rsqf(q0);
                float m0 = v.z * w0;
                float b0 = fmaf(v.y, w0, -v.z);
                float a0 = fmaf(m0, r0_, b0);
                float e0 = __builtin_amdgcn_exp2f(a0);
                float u0 = __builtin_amdgcn_rcpf(e0 + 1.f);
                // px1
                float w1 = xv1 + v.x;
                float q1 = fmaf(w1, w1, 0.04f);
                float r1_ = __builtin_amdgcn_rsqf(q1);
                float m1 = v.z * w1;
                float b1 = fmaf(v.y, w1, -v.z);
                float a1 = fmaf(m1, r1_, b1);
                float e1 = __builtin_amdgcn_exp2f(a1);
                float u1 = __builtin_amdgcn_rcpf(e1 + 1.f);
                if (kk == 0)      { s00 = fmaf(v.w, u0, s00); s10 = fmaf(v.w, u1, s10); }
                else if (kk == 1) { s01 = fmaf(v.w, u0, s01); s11 = fmaf(v.w, u1, s11); }
                else              { s02 = fmaf(v.w, u0, s02); s12 = fmaf(v.w, u1, s12); }
            }
        }
    }

    // ---- write per-wave partials: red[w][lr][col] ----
    red[w * 128 + (2 * ph + 0) * 32 + col] = (s00 + s01) + s02;
    red[w * 128 + (2 * ph + 1) * 32 + col] = (s10 + s11) + s12;
    __syncthreads();

    // ---- final: sum 4 cin-quartet waves, add constant, store once ----
    if (tid < 128) {
        int lr = tid >> 5;
        int cl = tid & 31;
        float v = red[0 * 128 + lr * 32 + cl] + red[1 * 128 + lr * 32 + cl]
                + red[2 * 128 + lr * 32 + cl] + red[3 * 128 + lr * 32 + cl]
                + csh + out_bias[co];
        out[((b * 32 + co) * 32 + (r0 + lr)) * 32 + cl] = v;
    }
}

extern "C" void kernel_launch(void* const* d_in, const int* in_sizes, int n_in,
                              void* d_out, int out_size, void* d_ws, size_t ws_size,
                              hipStream_t stream) {
    const float* x        = (const float*)d_in[0];
    const float* k        = (const float*)d_in[1];
    const float* Ec       = (const float*)d_in[2];
    const float* Ps       = (const float*)d_in[3];
    const float* bias     = (const float*)d_in[4];
    const float* coef     = (const float*)d_in[5];
    const float* out_bias = (const float*)d_in[6];
    float* out = (float*)d_out;

    ferro_main<<<dim3(1024), dim3(256), 0, stream>>>(
        x, k, Ec, Ps, bias, coef, out_bias, out);
}